// Round 1
// baseline (225.025 us; speedup 1.0000x reference)
//
#include <hip/hip_runtime.h>
#include <hip/hip_bf16.h>

#define BS      4096
#define SEGLEN  8192
#define LAMBDA1 8e-05f
#define LAMBDA2 8e-05f

// ---------------------------------------------------------------------------
// Kernel 1: per-row stats. One block (256 threads) per row.
//   smooth[row] = sum_{c=0..SEGLEN-2} (s[c+1]-s[c])^2
//   spars [row] = sum_c s[c]
//   ms    [row] = argmax_c s[c]   (FIRST occurrence on ties, like np.argmax)
// ---------------------------------------------------------------------------
__global__ __launch_bounds__(256) void row_stats(const float* __restrict__ scores,
                                                 float* __restrict__ smooth,
                                                 float* __restrict__ spars,
                                                 int*   __restrict__ ms) {
    const int row = blockIdx.x;
    const float* __restrict__ s = scores + (size_t)row * SEGLEN;
    const int t = threadIdx.x;

    float sum = 0.0f;
    float sq  = 0.0f;
    float mval = -1.0f;   // scores are uniform [0,1): any real score beats -1
    int   midx = SEGLEN;

    // SEGLEN/4 float4s, 256 threads -> 8 iterations, coalesced.
    #pragma unroll
    for (int k = 0; k < SEGLEN / 4 / 256; ++k) {
        const int c4 = t + k * 256;       // float4 index
        const int c0 = c4 * 4;            // element index
        const float4 v = ((const float4*)s)[c4];
        // neighbor for the last diff of this group; row end has no diff
        const float nxt = (c0 + 4 < SEGLEN) ? s[c0 + 4] : v.w;

        const float d0 = v.y - v.x;
        const float d1 = v.z - v.y;
        const float d2 = v.w - v.z;
        const float d3 = nxt - v.w;
        sq  += d0 * d0 + d1 * d1 + d2 * d2 + d3 * d3;
        sum += v.x + v.y + v.z + v.w;

        // strictly-greater keeps FIRST index (per-thread indices are increasing)
        if (v.x > mval) { mval = v.x; midx = c0;     }
        if (v.y > mval) { mval = v.y; midx = c0 + 1; }
        if (v.z > mval) { mval = v.z; midx = c0 + 2; }
        if (v.w > mval) { mval = v.w; midx = c0 + 3; }
    }

    // wave64 butterfly reduction
    #pragma unroll
    for (int off = 32; off > 0; off >>= 1) {
        sum += __shfl_xor(sum, off);
        sq  += __shfl_xor(sq,  off);
        const float ov = __shfl_xor(mval, off);
        const int   oi = __shfl_xor(midx, off);
        if (ov > mval || (ov == mval && oi < midx)) { mval = ov; midx = oi; }
    }

    __shared__ float ssum[4], ssq[4], smv[4];
    __shared__ int   smi[4];
    const int wave = t >> 6;
    if ((t & 63) == 0) { ssum[wave] = sum; ssq[wave] = sq; smv[wave] = mval; smi[wave] = midx; }
    __syncthreads();

    if (t == 0) {
        #pragma unroll
        for (int w = 1; w < 4; ++w) {
            sum += ssum[w];
            sq  += ssq[w];
            if (smv[w] > mval || (smv[w] == mval && smi[w] < midx)) { mval = smv[w]; midx = smi[w]; }
        }
        spars [row] = sum;
        smooth[row] = sq;
        ms    [row] = midx;
    }
}

// ---------------------------------------------------------------------------
// Kernel 2: margin + masked final sum. One block (256 threads) per row i;
// only rows with labels[i]==1 contribute.
//   margin[i] = sum_{j: labels[j]==0} max(0, 1 - ms[i] + ms[j])
//   out += (LAMBDA1*smooth[i] + LAMBDA2*spars[i] + margin[i]) / BS
// ---------------------------------------------------------------------------
__global__ __launch_bounds__(256) void margin_final(const float* __restrict__ smooth,
                                                    const float* __restrict__ spars,
                                                    const int*   __restrict__ ms,
                                                    const int*   __restrict__ labels,
                                                    float*       __restrict__ out) {
    const int i = blockIdx.x;
    if (labels[i] != 1) return;

    const int msi = ms[i];
    const int t = threadIdx.x;

    int acc = 0;  // max per block: 2048 neg * 8192 = 1.7e7 << INT_MAX
    for (int j = t; j < BS; j += 256) {
        if (labels[j] == 0) {
            const int v = 1 - msi + ms[j];
            acc += (v > 0) ? v : 0;
        }
    }

    #pragma unroll
    for (int off = 32; off > 0; off >>= 1)
        acc += __shfl_xor(acc, off);

    __shared__ int sacc[4];
    const int wave = t >> 6;
    if ((t & 63) == 0) sacc[wave] = acc;
    __syncthreads();

    if (t == 0) {
        acc += sacc[1] + sacc[2] + sacc[3];
        const float per = LAMBDA1 * smooth[i] + LAMBDA2 * spars[i] + (float)acc;
        atomicAdd(out, per * (1.0f / (float)BS));
    }
}

extern "C" void kernel_launch(void* const* d_in, const int* in_sizes, int n_in,
                              void* d_out, int out_size, void* d_ws, size_t ws_size,
                              hipStream_t stream) {
    const float* scores = (const float*)d_in[0];
    const int*   labels = (const int*)d_in[1];
    float*       out    = (float*)d_out;

    float* smooth = (float*)d_ws;
    float* spars  = smooth + BS;
    int*   ms     = (int*)(spars + BS);

    hipMemsetAsync(out, 0, sizeof(float), stream);

    row_stats<<<BS, 256, 0, stream>>>(scores, smooth, spars, ms);
    margin_final<<<BS, 256, 0, stream>>>(smooth, spars, ms, labels, out);
}

// Round 2
// 213.941 us; speedup vs baseline: 1.0518x; 1.0518x over previous
//
#include <hip/hip_runtime.h>
#include <hip/hip_bf16.h>

#define BS      4096
#define SEGLEN  8192
#define LAMBDA1 8e-05f
#define LAMBDA2 8e-05f

// ---------------------------------------------------------------------------
// Kernel 1: per-row stats. One block (256 threads) per row.
//   smooth[row] = sum_{c=0..SEGLEN-2} (s[c+1]-s[c])^2
//   spars [row] = sum_c s[c]
//   ms    [row] = argmax_c s[c]   (FIRST occurrence on ties, like np.argmax)
// Block 0 / thread 0 also zeroes d_out so kernel 2 can atomicAdd into it
// (stream dispatch order + kernel-boundary release make this coherent).
// ---------------------------------------------------------------------------
__global__ __launch_bounds__(256) void row_stats(const float* __restrict__ scores,
                                                 float* __restrict__ smooth,
                                                 float* __restrict__ spars,
                                                 int*   __restrict__ ms,
                                                 float* __restrict__ out) {
    const int row = blockIdx.x;
    const float* __restrict__ s = scores + (size_t)row * SEGLEN;
    const int t = threadIdx.x;

    if (row == 0 && t == 0) out[0] = 0.0f;

    float sum = 0.0f;
    float sq  = 0.0f;
    float mval = -1.0f;   // scores are uniform [0,1): any real score beats -1
    int   midx = SEGLEN;

    // SEGLEN/4 float4s, 256 threads -> 8 iterations, coalesced.
    #pragma unroll
    for (int k = 0; k < SEGLEN / 4 / 256; ++k) {
        const int c4 = t + k * 256;       // float4 index
        const int c0 = c4 * 4;            // element index
        const float4 v = ((const float4*)s)[c4];
        // neighbor for the last diff of this group; row end has no diff.
        // L1-hit: same/adjacent line as the float4 load above.
        const float nxt = (c0 + 4 < SEGLEN) ? s[c0 + 4] : v.w;

        const float d0 = v.y - v.x;
        const float d1 = v.z - v.y;
        const float d2 = v.w - v.z;
        const float d3 = nxt - v.w;
        sq  += d0 * d0 + d1 * d1 + d2 * d2 + d3 * d3;
        sum += v.x + v.y + v.z + v.w;

        // strictly-greater keeps FIRST index (per-thread indices are increasing)
        if (v.x > mval) { mval = v.x; midx = c0;     }
        if (v.y > mval) { mval = v.y; midx = c0 + 1; }
        if (v.z > mval) { mval = v.z; midx = c0 + 2; }
        if (v.w > mval) { mval = v.w; midx = c0 + 3; }
    }

    // wave64 butterfly reduction
    #pragma unroll
    for (int off = 32; off > 0; off >>= 1) {
        sum += __shfl_xor(sum, off);
        sq  += __shfl_xor(sq,  off);
        const float ov = __shfl_xor(mval, off);
        const int   oi = __shfl_xor(midx, off);
        if (ov > mval || (ov == mval && oi < midx)) { mval = ov; midx = oi; }
    }

    __shared__ float ssum[4], ssq[4], smv[4];
    __shared__ int   smi[4];
    const int wave = t >> 6;
    if ((t & 63) == 0) { ssum[wave] = sum; ssq[wave] = sq; smv[wave] = mval; smi[wave] = midx; }
    __syncthreads();

    if (t == 0) {
        #pragma unroll
        for (int w = 1; w < 4; ++w) {
            sum += ssum[w];
            sq  += ssq[w];
            if (smv[w] > mval || (smv[w] == mval && smi[w] < midx)) { mval = smv[w]; midx = smi[w]; }
        }
        spars [row] = sum;
        smooth[row] = sq;
        ms    [row] = midx;
    }
}

// ---------------------------------------------------------------------------
// Kernel 2: margin + masked final sum. 256 blocks x 256 threads.
// Block b owns i in [b*16, b*16+16). ms[] and labels[] staged in LDS (32 KB).
// Grand sum over (i pos, j neg) pairs of relu(1 - ms[i] + ms[j]) plus the
// lambda terms for pos i; one float atomicAdd per block.
// Per-block int32 bound: 16 * 4096 * 8192 = 5.4e8 < INT_MAX.
// ---------------------------------------------------------------------------
#define MB_BLOCKS 256
#define IPB (BS / MB_BLOCKS)   // 16 rows per block

__global__ __launch_bounds__(256) void margin_final(const float* __restrict__ smooth,
                                                    const float* __restrict__ spars,
                                                    const int*   __restrict__ ms,
                                                    const int*   __restrict__ labels,
                                                    float*       __restrict__ out) {
    __shared__ int ms_l[BS];
    __shared__ int lab_l[BS];

    const int t = threadIdx.x;
    const int b = blockIdx.x;

    for (int idx = t; idx < BS; idx += 256) {
        ms_l[idx]  = ms[idx];
        lab_l[idx] = labels[idx];
    }
    __syncthreads();

    int   macc = 0;    // hinge sum over this block's pos-i rows
    float facc = 0.0f; // lambda terms for this block's pos-i rows

    #pragma unroll
    for (int ii = 0; ii < IPB; ++ii) {
        const int i = b * IPB + ii;
        if (lab_l[i] == 1) {
            const int base = 1 - ms_l[i];
            for (int j = t; j < BS; j += 256) {
                if (lab_l[j] == 0) {
                    const int v = base + ms_l[j];
                    macc += (v > 0) ? v : 0;
                }
            }
        }
    }
    if (t < IPB) {
        const int i = b * IPB + t;
        if (lab_l[i] == 1)
            facc = LAMBDA1 * smooth[i] + LAMBDA2 * spars[i];
    }

    // block reduction
    #pragma unroll
    for (int off = 32; off > 0; off >>= 1) {
        macc += __shfl_xor(macc, off);
        facc += __shfl_xor(facc, off);
    }
    __shared__ int   sacc[4];
    __shared__ float sfac[4];
    const int wave = t >> 6;
    if ((t & 63) == 0) { sacc[wave] = macc; sfac[wave] = facc; }
    __syncthreads();

    if (t == 0) {
        macc += sacc[1] + sacc[2] + sacc[3];
        facc += sfac[1] + sfac[2] + sfac[3];
        const float partial = (facc + (float)macc) * (1.0f / (float)BS);
        if (partial != 0.0f) atomicAdd(out, partial);
    }
}

extern "C" void kernel_launch(void* const* d_in, const int* in_sizes, int n_in,
                              void* d_out, int out_size, void* d_ws, size_t ws_size,
                              hipStream_t stream) {
    const float* scores = (const float*)d_in[0];
    const int*   labels = (const int*)d_in[1];
    float*       out    = (float*)d_out;

    float* smooth = (float*)d_ws;
    float* spars  = smooth + BS;
    int*   ms     = (int*)(spars + BS);

    row_stats<<<BS, 256, 0, stream>>>(scores, smooth, spars, ms, out);
    margin_final<<<MB_BLOCKS, 256, 0, stream>>>(smooth, spars, ms, labels, out);
}